// Round 4
// baseline (174.532 us; speedup 1.0000x reference)
//
#include <hip/hip_runtime.h>
#include <math.h>
#include <stdint.h>

#define B_  64
#define N_  1024
#define M_  80
#define C1_ 288
#define D_  256
#define EPS_ 1e-12f

typedef _Float16 f16;
typedef _Float16 f16x8 __attribute__((ext_vector_type(8)));
typedef float    f32x4 __attribute__((ext_vector_type(4)));

// workspace layout (bytes)
#define ATT_OFF 0                        // 64*256*4       = 65536
#define W3F_OFF 65536                    // 9 planes *16KB = 147456
#define W4F_OFF (65536 + 147456)         // 8 planes *16KB = 131072
// total 344064 B (no h3 buffer anymore)

__device__ __forceinline__ void g2l16(const void* g, void* l) {
    __builtin_amdgcn_global_load_lds(
        (const __attribute__((address_space(1))) uint32_t*)g,
        (__attribute__((address_space(3))) uint32_t*)l, 16, 0, 0);
}

__device__ __forceinline__ uint32_t pk2(float a, float b) {
    union { f16 h[2]; uint32_t u; } c;
    c.h[0] = (f16)a; c.h[1] = (f16)b;
    return c.u;
}

__device__ __forceinline__ f16x8 w4_to_f16x8(uint32_t w0, uint32_t w1,
                                             uint32_t w2, uint32_t w3) {
    union { uint32_t u[4]; f16x8 h; } c;
    c.u[0] = w0; c.u[1] = w1; c.u[2] = w2; c.u[3] = w3;
    return c.h;
}

// ---------------- Kernel 1: prep (att pooling) + W3/W4 fragment repack ----------------
// softmax(score, axis=m) is invariant to the (oa@w_o)[b,n]+ba shift, so att
// depends only on b. Blocks 0..63: att. Blocks 64..80: repack one 32-deep
// kstep plane of W3/W4 into MFMA fragment order:
//   plane[nt][lane][i] = W[ks*32 + (lane>>4)*8 + i][nt*16 + (lane&15)]
__global__ __launch_bounds__(256) void prep_kernel(
    const float* __restrict__ lang_feat,   // B*M*D
    const int*   __restrict__ lang_mask,   // B*M
    const float* __restrict__ Wa,          // 2D x 1
    const float* __restrict__ W3,
    const float* __restrict__ W4,
    float* __restrict__ att_ws,            // B*D
    f16* __restrict__ w3f, f16* __restrict__ w4f)
{
    const int bi = blockIdx.x;
    if (bi >= B_) {
        const int kb = bi - B_;
        const float* src; f16* dst; int K0;
        if (kb < 9) { src = W3; dst = w3f + kb * 8192;       K0 = kb * 32; }
        else        { src = W4; dst = w4f + (kb - 9) * 8192; K0 = (kb - 9) * 32; }
        for (int idx = threadIdx.x; idx < 8192; idx += 256) {
            int nt  = idx >> 9;
            int rem = idx & 511;
            int ln  = rem >> 3;
            int i   = rem & 7;
            int k   = K0 + ((ln >> 4) << 3) + i;
            int col = (nt << 4) + (ln & 15);
            dst[idx] = (f16)src[k * D_ + col];
        }
        return;
    }

    __shared__ float wl_s[D_];
    __shared__ float ls[M_];
    const int b   = bi;
    const int tid = threadIdx.x;

    wl_s[tid] = Wa[D_ + tid];
    __syncthreads();

    const int wave = tid >> 6, lane = tid & 63;
    for (int m = wave; m < M_; m += 4) {
        const float* lf = lang_feat + (size_t)(b * M_ + m) * D_;
        float p = 0.f;
        #pragma unroll
        for (int j = 0; j < 4; ++j) { int d = lane + 64 * j; p = fmaf(lf[d], wl_s[d], p); }
        #pragma unroll
        for (int off = 32; off; off >>= 1) p += __shfl_xor(p, off);
        if (lane == 0) ls[m] = (lang_mask[b * M_ + m] == 0) ? -INFINITY : p;
    }
    __syncthreads();

    float mx = -INFINITY;
    #pragma unroll
    for (int m0 = 0; m0 < M_; m0 += 8) {
        float v0 = ls[m0], v1 = ls[m0+1], v2 = ls[m0+2], v3 = ls[m0+3];
        float v4 = ls[m0+4], v5 = ls[m0+5], v6 = ls[m0+6], v7 = ls[m0+7];
        mx = fmaxf(mx, fmaxf(fmaxf(fmaxf(v0,v1), fmaxf(v2,v3)),
                             fmaxf(fmaxf(v4,v5), fmaxf(v6,v7))));
    }
    __syncthreads();
    if (tid < M_) ls[tid] = expf(ls[tid] - mx);
    __syncthreads();

    float s0 = 0.f, s1 = 0.f, s2 = 0.f, s3 = 0.f;
    #pragma unroll
    for (int m0 = 0; m0 < M_; m0 += 8) {
        s0 += ls[m0] + ls[m0+4];
        s1 += ls[m0+1] + ls[m0+5];
        s2 += ls[m0+2] + ls[m0+6];
        s3 += ls[m0+3] + ls[m0+7];
    }
    const float inv = 1.f / ((s0 + s1) + (s2 + s3));

    const int d = tid;
    float a0 = 0.f, a1 = 0.f, a2 = 0.f, a3 = 0.f;
    const float* lfb = lang_feat + (size_t)b * M_ * D_ + d;
    #pragma unroll 5
    for (int m = 0; m < M_; m += 4) {
        a0 = fmaf(ls[m],   lfb[(size_t)m * D_],       a0);
        a1 = fmaf(ls[m+1], lfb[(size_t)(m+1) * D_],   a1);
        a2 = fmaf(ls[m+2], lfb[(size_t)(m+2) * D_],   a2);
        a3 = fmaf(ls[m+3], lfb[(size_t)(m+3) * D_],   a3);
    }
    att_ws[b * D_ + d] = ((a0 + a1) + (a2 + a3)) * inv;
}

// ---------------- Kernel 2: fully fused GEMM1 -> transpose -> GEMM2 -> epilogue ----------------
// Operand-swapped MFMAs: acc1 = mfma(w3frag, objfrag) gives h3^T frags
// (lane&15 = obj-row). ds_bpermute converts C/D frags to GEMM2 b-frags
// in-register. W4f is LDS-resident (barrier deferred under GEMM1).
__global__ __launch_bounds__(512, 2) void main_kernel(
    const float* __restrict__ obj,     // B*N*C1 fp32
    const f16*  __restrict__ w3f,      // 9 fragment planes (streamed from L2)
    const f16*  __restrict__ w4f,      // 8 fragment planes (LDS-resident)
    const float* __restrict__ b3,
    const float* __restrict__ b4,
    const float* __restrict__ Ws,
    const float* __restrict__ bs,
    const float* __restrict__ att,     // B*D
    float* __restrict__ out)           // B*N
{
    extern __shared__ char smem[];     // 131072 = W4f
    const int tid  = threadIdx.x;
    const int lane = tid & 63;
    const int w    = tid >> 6;         // 8 waves
    const int g    = lane & 15;        // obj-row within 16
    const int q    = lane >> 4;        // quad

    // issue W4f staging; completion barrier deferred until before GEMM2
    #pragma unroll
    for (int i = 0; i < 16; ++i) {
        int off = (i * 512 + tid) * 16;
        g2l16((const char*)w4f + off, smem + off);
    }

    const int r0w = (blockIdx.x * 8 + w) * 32;   // wave's 32 rows
    const int b   = blockIdx.x >> 2;             // 256 rows/block, 4 blocks/batch

    // ---- GEMM1 (swapped): acc[h][nt][r] = h3[row=16h+g][col=16nt+4q+r] ----
    f32x4 acc[2][16];
    #pragma unroll
    for (int nt = 0; nt < 16; ++nt) {
        f32x4 bv = *(const f32x4*)&b3[nt * 16 + q * 4];
        acc[0][nt] = bv; acc[1][nt] = bv;
    }

    const float* ap0 = obj + (size_t)(r0w + g) * C1_ + q * 8;
    const float* ap1 = ap0 + 16 * C1_;

    #pragma unroll 3
    for (int ks = 0; ks < 9; ++ks) {
        float4 p00 = *(const float4*)(ap0 + ks * 32);
        float4 p01 = *(const float4*)(ap0 + ks * 32 + 4);
        float4 p10 = *(const float4*)(ap1 + ks * 32);
        float4 p11 = *(const float4*)(ap1 + ks * 32 + 4);
        f16x8 o0 = {(f16)p00.x,(f16)p00.y,(f16)p00.z,(f16)p00.w,
                    (f16)p01.x,(f16)p01.y,(f16)p01.z,(f16)p01.w};
        f16x8 o1 = {(f16)p10.x,(f16)p10.y,(f16)p10.z,(f16)p10.w,
                    (f16)p11.x,(f16)p11.y,(f16)p11.z,(f16)p11.w};
        const f16* wp = w3f + ks * 8192;      // 16 KB plane, L1/L2-hot
        #pragma unroll
        for (int nt = 0; nt < 16; ++nt) {
            f16x8 wf = *(const f16x8*)(wp + nt * 512 + lane * 8);
            acc[0][nt] = __builtin_amdgcn_mfma_f32_16x16x32_f16(wf, o0, acc[0][nt], 0, 0, 0);
            acc[1][nt] = __builtin_amdgcn_mfma_f32_16x16x32_f16(wf, o1, acc[1][nt], 0, 0, 0);
        }
    }

    // ---- relu + pack: S[h][nt][rp] = f16x2(cols 16nt+4q+2rp, +1) of row g ----
    uint32_t S[2][16][2];
    #pragma unroll
    for (int h = 0; h < 2; ++h)
        #pragma unroll
        for (int nt = 0; nt < 16; ++nt) {
            S[h][nt][0] = pk2(fmaxf(acc[h][nt][0], 0.f), fmaxf(acc[h][nt][1], 0.f));
            S[h][nt][1] = pk2(fmaxf(acc[h][nt][2], 0.f), fmaxf(acc[h][nt][3], 0.f));
        }

    // ---- in-register transpose to GEMM2 b-frags via ds_bpermute ----
    // target word (Q=q, ks, p): src lane = g + 16*(2*(q&1)+(p>>1)),
    // src reg = S[2ks + (q>>1)][p&1]  -> 2 bpermutes + select on lane>=32
    const int a0 = (g + 32 * (q & 1)) * 4;
    const int a1 = a0 + 64;
    const bool hi = (lane >= 32);
    f16x8 hf[2][8];
    #pragma unroll
    for (int h = 0; h < 2; ++h)
        #pragma unroll
        for (int ks = 0; ks < 8; ++ks) {
            uint32_t wd[4];
            #pragma unroll
            for (int p = 0; p < 4; ++p) {
                int ad = (p >> 1) ? a1 : a0;
                int vA = __builtin_amdgcn_ds_bpermute(ad, (int)S[h][2*ks][p & 1]);
                int vB = __builtin_amdgcn_ds_bpermute(ad, (int)S[h][2*ks+1][p & 1]);
                wd[p] = hi ? (uint32_t)vB : (uint32_t)vA;
            }
            hf[h][ks] = w4_to_f16x8(wd[0], wd[1], wd[2], wd[3]);
        }

    // ---- GEMM2 (swapped): acc2[h][nt][r] = osc[row=16h+g][col=16nt+4q+r] ----
    f32x4 acc2[2][16];
    #pragma unroll
    for (int nt = 0; nt < 16; ++nt) {
        f32x4 bv = *(const f32x4*)&b4[nt * 16 + q * 4];
        acc2[0][nt] = bv; acc2[1][nt] = bv;
    }

    __syncthreads();   // W4f staging drained (overlapped with all of GEMM1)

    #pragma unroll
    for (int ks = 0; ks < 8; ++ks) {
        const char* bp = smem + ks * 16384;
        #pragma unroll
        for (int nt = 0; nt < 16; ++nt) {
            f16x8 wf = *(const f16x8*)&bp[nt * 1024 + lane * 16];
            acc2[0][nt] = __builtin_amdgcn_mfma_f32_16x16x32_f16(wf, hf[0][ks], acc2[0][nt], 0, 0, 0);
            acc2[1][nt] = __builtin_amdgcn_mfma_f32_16x16x32_f16(wf, hf[1][ks], acc2[1][nt], 0, 0, 0);
        }
    }

    // ---- epilogue: x=relu(att*osc); out=(x.Ws)/max(||x||,eps)+bs ----
    const float bsv = bs[0];
    float s2[2] = {0.f, 0.f}, sw[2] = {0.f, 0.f};
    #pragma unroll
    for (int nt = 0; nt < 16; ++nt) {
        f32x4 av = *(const f32x4*)&att[(b << 8) + nt * 16 + q * 4];
        f32x4 wv = *(const f32x4*)&Ws[nt * 16 + q * 4];
        #pragma unroll
        for (int h = 0; h < 2; ++h)
            #pragma unroll
            for (int r = 0; r < 4; ++r) {
                float x = fmaxf(av[r] * acc2[h][nt][r], 0.f);
                s2[h] = fmaf(x, x, s2[h]);
                sw[h] = fmaf(x, wv[r], sw[h]);
            }
    }
    #pragma unroll
    for (int h = 0; h < 2; ++h) {
        s2[h] += __shfl_xor(s2[h], 16);  sw[h] += __shfl_xor(sw[h], 16);
        s2[h] += __shfl_xor(s2[h], 32);  sw[h] += __shfl_xor(sw[h], 32);
    }
    if (lane < 16) {
        out[r0w + g]      = sw[0] / fmaxf(sqrtf(s2[0]), EPS_) + bsv;
        out[r0w + 16 + g] = sw[1] / fmaxf(sqrtf(s2[1]), EPS_) + bsv;
    }
}

extern "C" void kernel_launch(void* const* d_in, const int* in_sizes, int n_in,
                              void* d_out, int out_size, void* d_ws, size_t ws_size,
                              hipStream_t stream) {
    const float* object_feat = (const float*)d_in[0];
    const float* lang_feat   = (const float*)d_in[1];
    const int*   lang_mask   = (const int*)d_in[2];
    // d_in[3..6],[8] = W1,b1,W2,b2,ba : dead (softmax shift-invariance)
    const float* Wa = (const float*)d_in[7];
    const float* W3 = (const float*)d_in[9];
    const float* b3 = (const float*)d_in[10];
    const float* W4 = (const float*)d_in[11];
    const float* b4 = (const float*)d_in[12];
    const float* Ws = (const float*)d_in[13];
    const float* bs = (const float*)d_in[14];
    float* out = (float*)d_out;

    char* ws   = (char*)d_ws;
    float* att = (float*)(ws + ATT_OFF);
    f16*  w3f  = (f16*)(ws + W3F_OFF);
    f16*  w4f  = (f16*)(ws + W4F_OFF);

    hipFuncSetAttribute(reinterpret_cast<const void*>(main_kernel),
                        hipFuncAttributeMaxDynamicSharedMemorySize, 131072);

    prep_kernel<<<B_ + 17, 256, 0, stream>>>(lang_feat, lang_mask, Wa, W3, W4,
                                             att, w3f, w4f);
    main_kernel<<<256, 512, 131072, stream>>>(object_feat, w3f, w4f,
                                              b3, b4, Ws, bs, att, out);
}

// Round 6
// 167.733 us; speedup vs baseline: 1.0405x; 1.0405x over previous
//
#include <hip/hip_runtime.h>
#include <math.h>
#include <stdint.h>

#define B_  64
#define N_  1024
#define M_  80
#define C1_ 288
#define D_  256
#define EPS_ 1e-12f

typedef _Float16 f16;
typedef _Float16 f16x8 __attribute__((ext_vector_type(8)));
typedef float    f32x4 __attribute__((ext_vector_type(4)));

// workspace layout (bytes): att | 17 contiguous weight planes (9 w3 + 8 w4)
#define ATT_OFF 0                        // 64*256*4 = 65536
#define WALL_OFF 65536                   // 17 planes * 16384 = 278528

__device__ __forceinline__ void g2l16(const void* g, void* l) {
    __builtin_amdgcn_global_load_lds(
        (const __attribute__((address_space(1))) uint32_t*)g,
        (__attribute__((address_space(3))) uint32_t*)l, 16, 0, 0);
}

__device__ __forceinline__ uint32_t pk2(float a, float b) {
    union { f16 h[2]; uint32_t u; } c;
    c.h[0] = (f16)a; c.h[1] = (f16)b;
    return c.u;
}

__device__ __forceinline__ f16x8 mk8(uint32_t w0, uint32_t w1,
                                     uint32_t w2, uint32_t w3) {
    union { uint32_t u[4]; f16x8 h; } c;
    c.u[0] = w0; c.u[1] = w1; c.u[2] = w2; c.u[3] = w3;
    return c.h;
}

#define SB() __builtin_amdgcn_sched_barrier(0)

// ---------------- Kernel 1: prep (att pooling) + weight fragment repack ----------------
// softmax(score, axis=m) is invariant to the (oa@w_o)[b,n]+ba shift, so att
// depends only on b. Blocks 0..63: att. Blocks 64..80: repack one 32-deep
// kstep plane of W3 (planes 0..8) / W4 (planes 9..16) into fragment order:
//   plane[nt][lane][i] = W[ks*32 + (lane>>4)*8 + i][nt*16 + (lane&15)]
__global__ __launch_bounds__(256) void prep_kernel(
    const float* __restrict__ lang_feat,   // B*M*D
    const int*   __restrict__ lang_mask,   // B*M
    const float* __restrict__ Wa,          // 2D x 1
    const float* __restrict__ W3,
    const float* __restrict__ W4,
    float* __restrict__ att_ws,            // B*D
    f16* __restrict__ wall)                // 17 planes
{
    const int bi = blockIdx.x;
    if (bi >= B_) {
        const int kb = bi - B_;
        const float* src; int K0;
        if (kb < 9) { src = W3; K0 = kb * 32; }
        else        { src = W4; K0 = (kb - 9) * 32; }
        f16* dst = wall + kb * 8192;
        for (int idx = threadIdx.x; idx < 8192; idx += 256) {
            int nt  = idx >> 9;
            int rem = idx & 511;
            int ln  = rem >> 3;
            int i   = rem & 7;
            int k   = K0 + ((ln >> 4) << 3) + i;
            int col = (nt << 4) + (ln & 15);
            dst[idx] = (f16)src[k * D_ + col];
        }
        return;
    }

    __shared__ float wl_s[D_];
    __shared__ float ls[M_];
    const int b   = bi;
    const int tid = threadIdx.x;

    wl_s[tid] = Wa[D_ + tid];
    __syncthreads();

    const int wave = tid >> 6, lane = tid & 63;
    for (int m = wave; m < M_; m += 4) {
        const float* lf = lang_feat + (size_t)(b * M_ + m) * D_;
        float p = 0.f;
        #pragma unroll
        for (int j = 0; j < 4; ++j) { int d = lane + 64 * j; p = fmaf(lf[d], wl_s[d], p); }
        #pragma unroll
        for (int off = 32; off; off >>= 1) p += __shfl_xor(p, off);
        if (lane == 0) ls[m] = (lang_mask[b * M_ + m] == 0) ? -INFINITY : p;
    }
    __syncthreads();

    float mx = -INFINITY;
    #pragma unroll
    for (int m0 = 0; m0 < M_; m0 += 8) {
        float v0 = ls[m0], v1 = ls[m0+1], v2 = ls[m0+2], v3 = ls[m0+3];
        float v4 = ls[m0+4], v5 = ls[m0+5], v6 = ls[m0+6], v7 = ls[m0+7];
        mx = fmaxf(mx, fmaxf(fmaxf(fmaxf(v0,v1), fmaxf(v2,v3)),
                             fmaxf(fmaxf(v4,v5), fmaxf(v6,v7))));
    }
    __syncthreads();
    if (tid < M_) ls[tid] = expf(ls[tid] - mx);
    __syncthreads();

    float s0 = 0.f, s1 = 0.f, s2 = 0.f, s3 = 0.f;
    #pragma unroll
    for (int m0 = 0; m0 < M_; m0 += 8) {
        s0 += ls[m0] + ls[m0+4];
        s1 += ls[m0+1] + ls[m0+5];
        s2 += ls[m0+2] + ls[m0+6];
        s3 += ls[m0+3] + ls[m0+7];
    }
    const float inv = 1.f / ((s0 + s1) + (s2 + s3));

    const int d = tid;
    float a0 = 0.f, a1 = 0.f, a2 = 0.f, a3 = 0.f;
    const float* lfb = lang_feat + (size_t)b * M_ * D_ + d;
    #pragma unroll 5
    for (int m = 0; m < M_; m += 4) {
        a0 = fmaf(ls[m],   lfb[(size_t)m * D_],       a0);
        a1 = fmaf(ls[m+1], lfb[(size_t)(m+1) * D_],   a1);
        a2 = fmaf(ls[m+2], lfb[(size_t)(m+2) * D_],   a2);
        a3 = fmaf(ls[m+3], lfb[(size_t)(m+3) * D_],   a3);
    }
    att_ws[b * D_ + d] = ((a0 + a1) + (a2 + a3)) * inv;
}

// ---------------- Kernel 2: fused GEMM1 -> reg-transpose -> GEMM2 -> epilogue ----------
// 512 blocks x 8 waves x 16 rows; 2 blocks/CU (64 KB LDS, <=128 VGPR).
// 4-slot ring of weight planes staged by global_load_lds with counted vmcnt.
// ALL vmem issue order is pinned by sched_barrier(0) so the vmcnt ledger is
// exact:  prologue S0 S1 S2 O0 ; region k: O(k+1) | S(k+3).
// Swapped MFMAs: mfma(wfrag, objfrag) -> lane&15 = obj-row.
#define SLOT 16384

__global__ __launch_bounds__(512, 4) void main_kernel(
    const float* __restrict__ obj,     // B*N*C1 fp32
    const f16*  __restrict__ wall,     // 17 weight planes (w3f 0..8, w4f 9..16)
    const float* __restrict__ b3,
    const float* __restrict__ b4,
    const float* __restrict__ Ws,
    const float* __restrict__ bs,
    const float* __restrict__ att,     // B*D
    float* __restrict__ out)           // B*N
{
    __shared__ char smem[4 * SLOT];
    const int tid  = threadIdx.x;
    const int lane = tid & 63;
    const int w    = tid >> 6;         // 8 waves
    const int g    = lane & 15;        // obj-row within 16
    const int q    = lane >> 4;        // quad

    const int r0w = (blockIdx.x * 8 + w) * 16;   // this wave's 16 rows
    const int b   = r0w >> 10;

#define STAGE(p) do {                                                   \
        const char* _g = (const char*)wall + (p) * SLOT + tid * 16;     \
        char* _l = smem + ((p) & 3) * SLOT + tid * 16;                  \
        g2l16(_g, _l); g2l16(_g + 8192, _l + 8192);                     \
    } while (0)

    // ---- GEMM1 accumulators = b3 ----
    f32x4 acc[16];
    #pragma unroll
    for (int nt = 0; nt < 16; ++nt)
        acc[nt] = *(const f32x4*)&b3[nt * 16 + q * 4];

    // prologue (order pinned): S0 S0 | S1 S1 | S2 S2 | O0 O0
    STAGE(0); SB();
    STAGE(1); SB();
    STAGE(2); SB();
    const float* ap = obj + (size_t)(r0w + g) * C1_ + q * 8;
    float4 oc0 = *(const float4*)(ap);
    float4 oc1 = *(const float4*)(ap + 4);
    SB();

    // ---- GEMM1: 9 planes (K=288) ----
    #pragma unroll
    for (int k = 0; k < 9; ++k) {
        // ledger (pinned order): k=0 outstanding S0S0S1S1S2S2O0O0 -> vmcnt(4)
        // drains plane0. Steady state: plane k already drained by the
        // compiler's auto-wait for O(k-1) in iteration k-1 (O issued before
        // S in each region); vmcnt(6) is a no-op safety net.
        if (k == 0) asm volatile("s_waitcnt vmcnt(4)" ::: "memory");
        else        asm volatile("s_waitcnt vmcnt(6)" ::: "memory");
        __builtin_amdgcn_s_barrier();      // all waves' plane-k chunks landed
        SB();
        if (k < 8) {                       // obj prefetch FIRST (pinned)
            float4 on0 = *(const float4*)(ap + (k + 1) * 32);
            float4 on1 = *(const float4*)(ap + (k + 1) * 32 + 4);
            SB();
            STAGE(k + 3);                  // overwrites slot of plane k-1 (safe: barrier above)
            SB();
            f16x8 o = {(f16)oc0.x,(f16)oc0.y,(f16)oc0.z,(f16)oc0.w,
                       (f16)oc1.x,(f16)oc1.y,(f16)oc1.z,(f16)oc1.w};
            const char* bb = smem + (k & 3) * SLOT;
            #pragma unroll
            for (int nt = 0; nt < 16; ++nt) {
                f16x8 wf = *(const f16x8*)&bb[nt * 1024 + lane * 16];
                acc[nt] = __builtin_amdgcn_mfma_f32_16x16x32_f16(wf, o, acc[nt], 0, 0, 0);
            }
            oc0 = on0; oc1 = on1;
        } else {
            STAGE(11);                     // last GEMM1 region: stage plane 11 only
            SB();
            f16x8 o = {(f16)oc0.x,(f16)oc0.y,(f16)oc0.z,(f16)oc0.w,
                       (f16)oc1.x,(f16)oc1.y,(f16)oc1.z,(f16)oc1.w};
            const char* bb = smem + (k & 3) * SLOT;
            #pragma unroll
            for (int nt = 0; nt < 16; ++nt) {
                f16x8 wf = *(const f16x8*)&bb[nt * 1024 + lane * 16];
                acc[nt] = __builtin_amdgcn_mfma_f32_16x16x32_f16(wf, o, acc[nt], 0, 0, 0);
            }
        }
    }

    // ---- relu + pack + in-register transpose (ds_bpermute) ----
    // S[nt][rp] = f16x2 of h3 cols (16nt+4q+2rp, +1), row g.
    uint32_t S[16][2];
    #pragma unroll
    for (int nt = 0; nt < 16; ++nt) {
        S[nt][0] = pk2(fmaxf(acc[nt][0], 0.f), fmaxf(acc[nt][1], 0.f));
        S[nt][1] = pk2(fmaxf(acc[nt][2], 0.f), fmaxf(acc[nt][3], 0.f));
    }
    // target word (q,ks,p): src lane = g + 16*(2*(q&1)+(p>>1)),
    // src reg S[2ks+(q>>1)][p&1] -> 2 bpermutes + select on lane>=32
    const int a0 = (g + 32 * (q & 1)) * 4;
    const int a1 = a0 + 64;
    const bool hi = (lane >= 32);
    f16x8 hf[8];
    #pragma unroll
    for (int ks = 0; ks < 8; ++ks) {
        uint32_t wd[4];
        #pragma unroll
        for (int p = 0; p < 4; ++p) {
            int ad = (p >> 1) ? a1 : a0;
            int vA = __builtin_amdgcn_ds_bpermute(ad, (int)S[2*ks][p & 1]);
            int vB = __builtin_amdgcn_ds_bpermute(ad, (int)S[2*ks+1][p & 1]);
            wd[p] = hi ? (uint32_t)vB : (uint32_t)vA;
        }
        hf[ks] = mk8(wd[0], wd[1], wd[2], wd[3]);
    }

    // ---- GEMM2 accumulators = b4 ----
    f32x4 acc2[16];
    #pragma unroll
    for (int nt = 0; nt < 16; ++nt)
        acc2[nt] = *(const f32x4*)&b4[nt * 16 + q * 4];

    // ---- GEMM2: planes 9..16 (K=256) ----
    // ledger at entry: outstanding = S10 S10 S11 S11 (O8 auto-drained by its
    // use at k=8; S9 and older drained with it).  j=0 vmcnt(4): no-op, p9 ok.
    // j>=1: vmcnt(4) drains exactly plane 9+j.  Tail: vmcnt(2), vmcnt(0).
    #pragma unroll
    for (int j = 0; j < 8; ++j) {
        if (j < 6)       asm volatile("s_waitcnt vmcnt(4)" ::: "memory");
        else if (j == 6) asm volatile("s_waitcnt vmcnt(2)" ::: "memory");
        else             asm volatile("s_waitcnt vmcnt(0)" ::: "memory");
        __builtin_amdgcn_s_barrier();
        SB();
        if (j < 5) { STAGE(12 + j); SB(); }       // planes 12..16
        const char* bb = smem + ((9 + j) & 3) * SLOT;
        #pragma unroll
        for (int nt = 0; nt < 16; ++nt) {
            f16x8 wf = *(const f16x8*)&bb[nt * 1024 + lane * 16];
            acc2[nt] = __builtin_amdgcn_mfma_f32_16x16x32_f16(wf, hf[j], acc2[nt], 0, 0, 0);
        }
    }
#undef STAGE

    // ---- epilogue: x=relu(att*osc); out=(x.Ws)/max(||x||,eps)+bs ----
    const float bsv = bs[0];
    float s2 = 0.f, sw = 0.f;
    #pragma unroll
    for (int nt = 0; nt < 16; ++nt) {
        f32x4 av = *(const f32x4*)&att[(b << 8) + nt * 16 + q * 4];
        f32x4 wv = *(const f32x4*)&Ws[nt * 16 + q * 4];
        #pragma unroll
        for (int r = 0; r < 4; ++r) {
            float x = fmaxf(av[r] * acc2[nt][r], 0.f);
            s2 = fmaf(x, x, s2);
            sw = fmaf(x, wv[r], sw);
        }
    }
    s2 += __shfl_xor(s2, 16);  sw += __shfl_xor(sw, 16);
    s2 += __shfl_xor(s2, 32);  sw += __shfl_xor(sw, 32);
    if (lane < 16)
        out[r0w + g] = sw / fmaxf(sqrtf(s2), EPS_) + bsv;
}

extern "C" void kernel_launch(void* const* d_in, const int* in_sizes, int n_in,
                              void* d_out, int out_size, void* d_ws, size_t ws_size,
                              hipStream_t stream) {
    const float* object_feat = (const float*)d_in[0];
    const float* lang_feat   = (const float*)d_in[1];
    const int*   lang_mask   = (const int*)d_in[2];
    // d_in[3..6],[8] = W1,b1,W2,b2,ba : dead (softmax shift-invariance)
    const float* Wa = (const float*)d_in[7];
    const float* W3 = (const float*)d_in[9];
    const float* b3 = (const float*)d_in[10];
    const float* W4 = (const float*)d_in[11];
    const float* b4 = (const float*)d_in[12];
    const float* Ws = (const float*)d_in[13];
    const float* bs = (const float*)d_in[14];
    float* out = (float*)d_out;

    char* ws    = (char*)d_ws;
    float* att  = (float*)(ws + ATT_OFF);
    f16*  wall  = (f16*)(ws + WALL_OFF);   // planes 0..8 = W3, 9..16 = W4

    prep_kernel<<<B_ + 17, 256, 0, stream>>>(lang_feat, lang_mask, Wa, W3, W4,
                                             att, wall);
    main_kernel<<<512, 512, 0, stream>>>(object_feat, wall,
                                         b3, b4, Ws, bs, att, out);
}